// Round 7
// baseline (781.918 us; speedup 1.0000x reference)
//
#include <hip/hip_runtime.h>
#include <stdint.h>

// ---------- helpers ----------
__device__ inline float bf2f(unsigned short u) { return __uint_as_float(((unsigned int)u) << 16); }
__device__ inline unsigned short f2bf(float f) {
    unsigned int x = __float_as_uint(f);
    unsigned int r = x + 0x7fffu + ((x >> 16) & 1u);   // RNE
    return (unsigned short)(r >> 16);
}

typedef __attribute__((ext_vector_type(8))) short bf16x8;
typedef __attribute__((ext_vector_type(4))) float f32x4;
typedef __attribute__((ext_vector_type(4))) int   v4i;
typedef __attribute__((ext_vector_type(4))) unsigned short u16x4;

#define FLAG_CAP 8192
#define MARGIN 0.02

// async global->LDS, 16B per lane; LDS dest = wave-uniform base + lane*16
__device__ inline void gload16(const void* g, void* l) {
    __builtin_amdgcn_global_load_lds(
        (const __attribute__((address_space(1))) void*)g,
        (__attribute__((address_space(3))) void*)l, 16, 0, 0);
}

// ---------- MFMA GEMM: C[M,N] = A[M,K] * Bt[N,K]^T (A,Bt bf16) ----------
// grid: x = n-tile (fast), y = m-tile, z = optional set index (score path).
// K-loop: BK=32, double-buffered (stage k+1 into buf^1 before computing k; one
// vmcnt-draining __syncthreads per step). R6: 789 -> 766us vs BK=64 single-buf.
// Kept as a single __global__ with RUNTIME dims: R5 showed const-folded K (merged
// launch) regressed ~30% (full-unroll bloat). No XCD swizzle (R2: +2.4%, cf. m160).
// mode 0: store bf16. mode 2: store f32 with rowMap scatter.
// mode 3: fused bio epilogue: atomicAdd fpart[row][c] += sum_n relu(v+fb1[n])*fw2[n][c]
__global__ __launch_bounds__(256) void gemm_bt(
    const unsigned short* __restrict__ A,
    const unsigned short* __restrict__ Bt,
    void* __restrict__ C,
    const int* __restrict__ Mdev,
    const int* __restrict__ rowMap,
    const float* __restrict__ fb1,
    const float* __restrict__ fw2,
    float* __restrict__ fpart,
    int M, int N, int K, int lda, int ldb, int ldc, int mode, int rowOff,
    size_t zA, int zMeta, int zMap, size_t zC)
{
    int zz = blockIdx.z;
    A += (size_t)zz * zA;
    if (Mdev) M = Mdev[zz * zMeta];
    if (rowMap) rowMap += (size_t)zz * zMap;

    int nt = blockIdx.x, mt = blockIdx.y;
    if (rowOff + mt * 128 >= M) return;

    __shared__ __align__(16) unsigned short As[2][128 * 32];
    __shared__ __align__(16) unsigned short Bs[2][128 * 32];

    int tid  = threadIdx.x;
    int lane = tid & 63, wave = tid >> 6;
    int wRow = (wave >> 1) * 64, wCol = (wave & 1) * 64;
    int mBase = mt * 128, nBase = nt * 128;
    int lm = lane & 15, kg = lane >> 4;
    int sr = tid >> 2;            // staging row 0..63 (+64*i)
    int sc = (tid & 3) * 8;       // staging col (8 elems = 16B)

    // Staging layout: element idx = tid*8 + i*2048 in a [128][32] tile ->
    // LDS dest = wave-uniform (wave*512 + i*2048 elems) + lane*16B  (DMA-legal).
    auto STAGE = [&](int k0, int buf) {
#pragma unroll
        for (int i = 0; i < 2; ++i) {
            int r = sr + 64 * i;
            int gm = rowOff + mBase + r; if (gm > M - 1) gm = M - 1;
            gload16(&A[(size_t)(gm - rowOff) * lda + k0 + sc], &As[buf][wave * 512 + i * 2048]);
            int gn = nBase + r; if (gn > N - 1) gn = N - 1;
            gload16(&Bt[(size_t)gn * ldb + k0 + sc], &Bs[buf][wave * 512 + i * 2048]);
        }
    };

    f32x4 acc[4][4] = {};

    STAGE(0, 0);
    __syncthreads();                       // drains vmcnt(0): buf0 ready
    int nsteps = K >> 5;
    for (int s = 0; s < nsteps; ++s) {
        int cur = s & 1;
        if (s + 1 < nsteps) STAGE((s + 1) << 5, cur ^ 1);   // overlap w/ compute
        bf16x8 af[4], bfr[4];
#pragma unroll
        for (int i = 0; i < 4; ++i) {
            af[i]  = *(const bf16x8*)&As[cur][(wRow + i * 16 + lm) * 32 + kg * 8];
            bfr[i] = *(const bf16x8*)&Bs[cur][(wCol + i * 16 + lm) * 32 + kg * 8];
        }
#pragma unroll
        for (int mi = 0; mi < 4; ++mi)
#pragma unroll
            for (int ni = 0; ni < 4; ++ni)
                acc[mi][ni] = __builtin_amdgcn_mfma_f32_16x16x32_bf16(
                    af[mi], bfr[ni], acc[mi][ni], 0, 0, 0);
        __syncthreads();                   // drains vmcnt(0): next buf ready;
    }                                      // also fences reads of cur before reuse

    int rbase = (lane >> 4) * 4;

    if (mode == 3) {
        float b1v[4], w2l[4][3];
#pragma unroll
        for (int ni = 0; ni < 4; ++ni) {
            int n = nBase + wCol + ni * 16 + lm;
            b1v[ni] = fb1[n];
#pragma unroll
            for (int c = 0; c < 3; ++c) w2l[ni][c] = fw2[n * 3 + c];
        }
#pragma unroll
        for (int mi = 0; mi < 4; ++mi) {
            float p2[4][3] = {};
#pragma unroll
            for (int ni = 0; ni < 4; ++ni)
#pragma unroll
                for (int r = 0; r < 4; ++r) {
                    float v = acc[mi][ni][r] + b1v[ni];
                    v = fmaxf(v, 0.f);
                    p2[r][0] += v * w2l[ni][0];
                    p2[r][1] += v * w2l[ni][1];
                    p2[r][2] += v * w2l[ni][2];
                }
#pragma unroll
            for (int r = 0; r < 4; ++r)
#pragma unroll
                for (int c = 0; c < 3; ++c) {
                    float s = p2[r][c];
                    s += __shfl_down(s, 8); s += __shfl_down(s, 4);
                    s += __shfl_down(s, 2); s += __shfl_down(s, 1);
                    p2[r][c] = s;
                }
            if (lm == 0) {
#pragma unroll
                for (int r = 0; r < 4; ++r) {
                    int row = mBase + wRow + mi * 16 + rbase + r;
#pragma unroll
                    for (int c = 0; c < 3; ++c)
                        atomicAdd(&fpart[(size_t)row * 3 + c], p2[r][c]);
                }
            }
        }
        return;
    }

#pragma unroll
    for (int mi = 0; mi < 4; ++mi) {
#pragma unroll
        for (int r = 0; r < 4; ++r) {
            int m = rowOff + mBase + wRow + mi * 16 + rbase + r;
            if (m >= M) continue;
            size_t crow = rowMap ? (size_t)rowMap[m] * ldc : (size_t)(m - rowOff) * ldc;
#pragma unroll
            for (int ni = 0; ni < 4; ++ni) {
                int n = nBase + wCol + ni * 16 + lm;
                if (n >= N) continue;
                float v = acc[mi][ni][r];
                if (mode == 2) ((float*)C)[(size_t)zz * zC + crow + n] = v;
                else           ((unsigned short*)C)[crow + n] = f2bf(v);
            }
        }
    }
}

// ---------- single fused prep kernel ----------
// block ranges: [0,373) zero-fill region | [373,1123) ent cast | [1123,25699) hidden cast
//             | [25699,26515) transposes (wd, w1) | [26515,27415) wm cast_pad
__global__ __launch_bounds__(256) void prep_all(
    const float* __restrict__ ent, unsigned short* __restrict__ entB,
    const float* __restrict__ hidden, unsigned short* __restrict__ hiddenB,
    const float* __restrict__ wd, unsigned short* __restrict__ wdT,
    const float* __restrict__ w1, unsigned short* __restrict__ w1T,
    const float* __restrict__ wm, unsigned short* __restrict__ wmP,
    v4i* __restrict__ zreg)
{
    __shared__ float tile[32][33];
    int b = blockIdx.x, t = threadIdx.x;
    if (b < 373) {
        int i = b * 256 + t;
        if (i < 95312) { v4i z = {0, 0, 0, 0}; zreg[i] = z; }
        return;
    }
    b -= 373;
    if (b < 750) {                                   // ent: 192000 float4
        int i = b * 256 + t;
        float4 v = ((const float4*)ent)[i];
        u16x4 o = { f2bf(v.x), f2bf(v.y), f2bf(v.z), f2bf(v.w) };
        ((u16x4*)entB)[i] = o;
        return;
    }
    b -= 750;
    if (b < 24576) {                                 // hidden: 6291456 float4
        int i = b * 256 + t;
        float4 v = ((const float4*)hidden)[i];
        u16x4 o = { f2bf(v.x), f2bf(v.y), f2bf(v.z), f2bf(v.w) };
        ((u16x4*)hiddenB)[i] = o;
        return;
    }
    b -= 24576;
    if (b < 240 + 576) {                             // transpose_cast wd / w1
        const float* in; unsigned short* out; int R, C, bx, by;
        if (b < 240) { in = wd; out = wdT; R = 768; C = 300; bx = b % 10; by = b / 10; }
        else { int bb = b - 240; in = w1; out = w1T; R = 768; C = 768; bx = bb % 24; by = bb / 24; }
        int tx = t & 31, ty = t >> 5;
        int c0 = bx * 32, r0 = by * 32;
#pragma unroll
        for (int i = 0; i < 4; ++i) {
            int r = r0 + ty + i * 8, c = c0 + tx;
            if (r < R && c < C) tile[ty + i * 8][tx] = in[(size_t)r * C + c];
        }
        __syncthreads();
#pragma unroll
        for (int i = 0; i < 4; ++i) {
            int orow = c0 + ty + i * 8, ocol = r0 + tx;
            if (orow < C && ocol < R) out[(size_t)orow * R + ocol] = f2bf(tile[tx][ty + i * 8]);
        }
        return;
    }
    b -= 816;
    {                                                // wm cast_pad 768x300 -> ld 320
        int idx = b * 256 + t;
        if (idx < 768 * 300) wmP[(size_t)(idx / 300) * 320 + (idx % 300)] = f2bf(wm[idx]);
    }
}

// ---------- finalize approx logits, flag marginal tokens ----------
__global__ void bio_final2(const float* __restrict__ part, const float* __restrict__ b2,
                           float* __restrict__ out0, int* __restrict__ predLab,
                           int* __restrict__ flagCnt, int* __restrict__ flagList)
{
    int t = blockIdx.x * 256 + threadIdx.x;
    double a[3];
#pragma unroll
    for (int c = 0; c < 3; ++c) a[c] = (double)part[(size_t)t * 3 + c] + (double)b2[c];
    double mx = a[0]; if (a[1] > mx) mx = a[1]; if (a[2] > mx) mx = a[2];
    double ls = mx + log(exp(a[0] - mx) + exp(a[1] - mx) + exp(a[2] - mx));
    out0[t * 3 + 0] = (float)(a[0] - ls);
    out0[t * 3 + 1] = (float)(a[1] - ls);
    out0[t * 3 + 2] = (float)(a[2] - ls);
    int pbest = 0; double bv = a[0];
    if (a[1] > bv) { bv = a[1]; pbest = 1; }
    if (a[2] > bv) { bv = a[2]; pbest = 2; }
    predLab[t] = pbest;
    double second = -1e300;
#pragma unroll
    for (int c = 0; c < 3; ++c) if (c != pbest && a[c] > second) second = a[c];
    if (bv - second < MARGIN) {
        int i = atomicAdd(flagCnt, 1);
        if (i < FLAG_CAP) flagList[i] = t;
    }
}

// ---------- exact f32 h1+partial-logit GEMM on flagged rows (reads hidden via flagList) ----------
__global__ __launch_bounds__(256) void h1_bio_gemm(
    const float* __restrict__ hidden, const int* __restrict__ flagList,
    const float* __restrict__ W,
    const float* __restrict__ b1, const float* __restrict__ w2,
    float* __restrict__ part, const int* __restrict__ Mdev, int partStride)
{
    int M = *Mdev; if (M > FLAG_CAP) M = FLAG_CAP;
    if (M <= 0) return;
    int m0 = blockIdx.x * 64, n0 = blockIdx.y * 64;
    if (m0 >= M) return;
    __shared__ float AsT[16][64];
    __shared__ float Ws[16][64];
    int tx = threadIdx.x, ty = threadIdx.y;
    int tid = ty * 16 + tx;
    float acc[4][4] = {};

    for (int k0 = 0; k0 < 768; k0 += 16) {
        __syncthreads();
        {
            int row = tid >> 2, seg = (tid & 3) * 4;
            int gm = m0 + row; if (gm > M - 1) gm = M - 1;
            float4 v = *(const float4*)&hidden[(size_t)flagList[gm] * 768 + k0 + seg];
            AsT[seg + 0][row] = v.x; AsT[seg + 1][row] = v.y;
            AsT[seg + 2][row] = v.z; AsT[seg + 3][row] = v.w;
        }
        {
            int row = tid >> 4, seg = (tid & 15) * 4;
            *(float4*)&Ws[row][seg] = *(const float4*)&W[(size_t)(k0 + row) * 768 + n0 + seg];
        }
        __syncthreads();
#pragma unroll
        for (int kk = 0; kk < 16; ++kk) {
            float4 av = *(const float4*)&AsT[kk][ty * 4];
            float4 bv = *(const float4*)&Ws[kk][tx * 4];
            float a[4] = {av.x, av.y, av.z, av.w};
            float b[4] = {bv.x, bv.y, bv.z, bv.w};
#pragma unroll
            for (int i = 0; i < 4; ++i)
#pragma unroll
                for (int j = 0; j < 4; ++j)
                    acc[i][j] += a[i] * b[j];
        }
    }

    float b1v[4], w2l[4][3];
#pragma unroll
    for (int j = 0; j < 4; ++j) {
        int n = n0 + tx * 4 + j;
        b1v[j] = b1[n];
#pragma unroll
        for (int c = 0; c < 3; ++c) w2l[j][c] = w2[n * 3 + c];
    }
    float p[4][3] = {};
#pragma unroll
    for (int i = 0; i < 4; ++i)
#pragma unroll
        for (int j = 0; j < 4; ++j) {
            float v = acc[i][j] + b1v[j];
            v = fmaxf(v, 0.f);
#pragma unroll
            for (int c = 0; c < 3; ++c) p[i][c] += v * w2l[j][c];
        }
#pragma unroll
    for (int i = 0; i < 4; ++i)
#pragma unroll
        for (int c = 0; c < 3; ++c) {
            float s = p[i][c];
            s += __shfl_down(s, 8); s += __shfl_down(s, 4);
            s += __shfl_down(s, 2); s += __shfl_down(s, 1);
            p[i][c] = s;
        }
    if (tx == 0) {
#pragma unroll
        for (int i = 0; i < 4; ++i) {
            int t = m0 + ty * 4 + i;
            if (t >= M) continue;
#pragma unroll
            for (int c = 0; c < 3; ++c)
                part[(size_t)blockIdx.y * partStride + (size_t)t * 3 + c] = p[i][c];
        }
    }
}

// ---------- merged segmentation prep, both sets (block 0 = true, block 1 = predicted) ----------
// Block 1 first applies the exact-rescue argmax fixes to predLab (folded bio_final_fix),
// then both blocks scan, emit stream/cum/map, and compute segment boundaries (folded
// seg_bound). Fold pattern validated in R2/R4 runs (passed, absmax 0.25).
// meta[set*64 + {0,1,2}] = numB, K, idx0
__global__ __launch_bounds__(1024) void seg_prep2(
    const int* __restrict__ labels, int* predLab,
    int* __restrict__ streamTok, int* __restrict__ cumArr,
    int* __restrict__ meta, int* __restrict__ rowC, int* __restrict__ mapArr,
    int* __restrict__ segFirst,
    const float* __restrict__ partF, const float* __restrict__ b2,
    const int* __restrict__ flagList, const int* __restrict__ flagCnt, int partStride)
{
    int setz = blockIdx.x;
    int t = threadIdx.x;

    if (setz == 1) {   // folded bio_final_fix (uniform branch within block)
        int cnt = *flagCnt; if (cnt > FLAG_CAP) cnt = FLAG_CAP;
        for (int i = t; i < cnt; i += 1024) {
            double a[3] = {(double)b2[0], (double)b2[1], (double)b2[2]};
#pragma unroll
            for (int blk = 0; blk < 12; ++blk)
#pragma unroll
                for (int c = 0; c < 3; ++c)
                    a[c] += (double)partF[(size_t)blk * partStride + (size_t)i * 3 + c];
            int pbest = 0; double bv = a[0];
            if (a[1] > bv) { bv = a[1]; pbest = 1; }
            if (a[2] > bv) { bv = a[2]; pbest = 2; }
            predLab[flagList[i]] = pbest;
        }
        __syncthreads();   // same-CU: fixed predLab visible to whole block
    }

    const int* lab = setz ? predLab : labels;
    int* sTok = streamTok + setz * 32768;
    int* sCum = cumArr + setz * 32768;
    int* mt   = meta + setz * 64;
    int* rC   = rowC + setz * 64;
    int* mp   = mapArr + setz * 32768;
    int* sf   = segFirst + setz * 32768;

    __shared__ int sM[1024], sB[1024];
    __shared__ int sRowC[64], sRowStart[64];
    __shared__ int sIdx0;
    if (t == 0) sIdx0 = 0x7fffffff;
    int base = t * 32;
    int vals[32];
#pragma unroll
    for (int j = 0; j < 8; ++j) {
        v4i v = ((const v4i*)lab)[t * 8 + j];
        vals[4 * j + 0] = v[0]; vals[4 * j + 1] = v[1];
        vals[4 * j + 2] = v[2]; vals[4 * j + 3] = v[3];
    }
    int mc = 0, bc = 0;
#pragma unroll
    for (int i = 0; i < 32; ++i) { mc += (vals[i] != 0); bc += (vals[i] == 1); }
    sM[t] = mc; sB[t] = bc; __syncthreads();
    for (int off = 1; off < 1024; off <<= 1) {
        int vm = 0, vb = 0;
        if (t >= off) { vm = sM[t - off]; vb = sB[t - off]; }
        __syncthreads();
        sM[t] += vm; sB[t] += vb;
        __syncthreads();
    }
    int mBase = sM[t] - mc, bBase = sB[t] - bc;
    int mRun = 0, bRun = 0;
#pragma unroll
    for (int i = 0; i < 32; ++i) {
        int v = vals[i];
        if (v != 0) {
            int q = mBase + mRun;
            sTok[q] = base + i;
            int isB = (v == 1);
            sCum[q] = bBase + bRun + isB;
            if (isB && (bBase + bRun) == 0) sIdx0 = q;   // unique thread
            mRun += 1; bRun += isB;
        }
    }
    if ((t & 15) == 0) sRowStart[t >> 4] = bBase;
    __syncthreads();
    if ((t & 15) == 0) {
        int b = t >> 4;
        sRowC[b] = sB[t + 15] - sRowStart[b];
        rC[b] = sRowC[b];
    }
    if (t == 1023) { mt[0] = sB[1023]; mt[1] = sM[1023]; }
    if (t == 0) mt[2] = (sIdx0 == 0x7fffffff) ? 0 : sIdx0;
    __syncthreads();
    for (int idx = t; idx < 32768; idx += 1024) {
        int b = idx >> 9, j = idx & 511;
        if (j < sRowC[b]) mp[sRowStart[b] + j] = idx;
    }

    // folded seg_bound: seg(q) nondecreasing in q; boundary -> segFirst[s] = q.
    int K = sM[1023], numB = sB[1023];
    int idx0 = (sIdx0 == 0x7fffffff) ? 0 : sIdx0;
    for (int q = t; q < K; q += 1024) {
        int qq = q + idx0;
        int c  = (qq < K) ? sCum[qq] : numB;
        int sg = c - 1;
        if (sg < 0) continue;
        int sp = -1;
        if (q > 0) {
            int qq2 = qq - 1;
            int c2  = (qq2 < K) ? sCum[qq2] : numB;
            sp = c2 - 1;
        }
        if (sg != sp) sf[sg] = q;
    }
}

// ---------- means for all segments, both sets (192 thr, u16x4 loads; R1/R6 form) ----------
__global__ __launch_bounds__(192) void seg_means2(
    const unsigned short* __restrict__ hiddenB, const int* __restrict__ streamTok,
    const int* __restrict__ segFirst, const int* __restrict__ meta,
    unsigned short* __restrict__ means, size_t zMeans)
{
    int setz = blockIdx.y;
    const int* mt = meta + setz * 64;
    int s = blockIdx.x;
    int numB = mt[0];
    if (s >= numB) return;
    const int* st = streamTok + setz * 32768;
    const int* sf = segFirst + setz * 32768;
    int q0 = sf[s];
    int q1 = (s + 1 < numB) ? sf[s + 1] : mt[1];
    int cnt = q1 - q0;                                   // >= 1 by construction
    int t = threadIdx.x;
    float a0 = 0.f, a1 = 0.f, a2 = 0.f, a3 = 0.f;
    for (int i = 0; i < cnt; ++i) {
        const unsigned short* hr = hiddenB + (size_t)st[q0 + i] * 768;
        u16x4 v = *(const u16x4*)&hr[t * 4];
        a0 += bf2f(v[0]); a1 += bf2f(v[1]); a2 += bf2f(v[2]); a3 += bf2f(v[3]);
    }
    float fc = (float)cnt;
    u16x4 o = { f2bf(a0 / fc), f2bf(a1 / fc), f2bf(a2 / fc), f2bf(a3 / fc) };
    *(u16x4*)&means[(size_t)setz * zMeans + (size_t)s * 768 + t * 4] = o;
}

// ---------- row log_softmax over 1000 cols + constant fill, both sets ----------
// float4 I/O (row base = v*4000 B, 16B-aligned), wave shfl_xor reduction:
// 2 barriers/row instead of 16. Validated in R5 run (passed, absmax 0.25).
__global__ __launch_bounds__(256) void softmax_rows2(float* __restrict__ outBase,
                                                     const int* __restrict__ rowCBase,
                                                     size_t zC)
{
    float* out = outBase + (size_t)blockIdx.y * zC;
    const int* rowC = rowCBase + blockIdx.y * 64;
    int v = blockIdx.x;
    int b = v >> 9, j = v & 511;
    int t = threadIdx.x;
    float* row = out + (size_t)v * 1000;
    bool act = t < 250;
    if (j >= rowC[b]) {
        if (act) {
            float4 f; f.x = f.y = f.z = f.w = -6.907755278982137f;
            ((float4*)row)[t] = f;
        }
        return;
    }
    __shared__ float wr[4], ws[4];
    int wave = t >> 6, lane = t & 63;
    float4 x;
    if (act) x = ((const float4*)row)[t];
    else { x.x = x.y = x.z = x.w = -1e30f; }
    float mx = fmaxf(fmaxf(x.x, x.y), fmaxf(x.z, x.w));
#pragma unroll
    for (int o = 32; o > 0; o >>= 1) mx = fmaxf(mx, __shfl_xor(mx, o));
    if (lane == 0) wr[wave] = mx;
    __syncthreads();
    float M = fmaxf(fmaxf(wr[0], wr[1]), fmaxf(wr[2], wr[3]));
    float sm = act ? (expf(x.x - M) + expf(x.y - M) + expf(x.z - M) + expf(x.w - M)) : 0.f;
#pragma unroll
    for (int o = 32; o > 0; o >>= 1) sm += __shfl_xor(sm, o);
    if (lane == 0) ws[wave] = sm;
    __syncthreads();
    float ls = M + logf(ws[0] + ws[1] + ws[2] + ws[3]);
    if (act) {
        x.x -= ls; x.y -= ls; x.z -= ls; x.w -= ls;
        ((float4*)row)[t] = x;
    }
}

// ---------- launch ----------
extern "C" void kernel_launch(void* const* d_in, const int* in_sizes, int n_in,
                              void* d_out, int out_size, void* d_ws, size_t ws_size,
                              hipStream_t stream)
{
    (void)in_sizes; (void)n_in; (void)out_size; (void)ws_size;
    const int*   labels = (const int*)d_in[0];
    const float* hidden = (const float*)d_in[1];
    const float* ent    = (const float*)d_in[2];
    const float* w1     = (const float*)d_in[3];
    const float* b1     = (const float*)d_in[4];
    const float* w2     = (const float*)d_in[5];
    const float* b2     = (const float*)d_in[6];
    const float* wm     = (const float*)d_in[7];
    const float* wd     = (const float*)d_in[8];

    char* ws = (char*)d_ws;
    size_t off = 0;
    auto alloc = [&](size_t bytes) {
        void* p = ws + off;
        off = (off + bytes + 255) & ~(size_t)255;
        return p;
    };
    int* meta      = (int*)alloc(512);                    // 2 sets x 64 ints
    int* rowC      = (int*)alloc(512);
    int* predLab   = (int*)alloc(32768 * 4);
    int* streamTok = (int*)alloc(2 * 32768 * 4);
    int* cumArr    = (int*)alloc(2 * 32768 * 4);
    int* segFirst  = (int*)alloc(2 * 32768 * 4);
    int* mapArr    = (int*)alloc(2 * 32768 * 4);
    int* flagList  = (int*)alloc(FLAG_CAP * 4);
    unsigned short* entB = (unsigned short*)alloc((size_t)1000 * 768 * 2);
    unsigned short* wdT  = (unsigned short*)alloc((size_t)300 * 768 * 2);
    unsigned short* W2t  = (unsigned short*)alloc((size_t)1000 * 768 * 2);
    unsigned short* w1T  = (unsigned short*)alloc((size_t)768 * 768 * 2);
    unsigned short* hiddenB = (unsigned short*)alloc((size_t)32768 * 768 * 2);   // 48 MB
    float* partF = (float*)alloc((size_t)12 * FLAG_CAP * 3 * 4);
    // contiguous zero region cleared by prep_all: [pd | wmP | part | flagCnt]
    char* zbase = (char*)alloc(1524992);
    unsigned short* pd  = (unsigned short*)zbase;                 // 1000x320 bf16 = 640000 B
    unsigned short* wmP = (unsigned short*)(zbase + 640000);      // 768x320 bf16  = 491520 B
    float* part         = (float*)(zbase + 1131520);              // 32768x3 f32   = 393216 B
    int* flagCnt        = (int*)(zbase + 1524736);                // 256 B
    unsigned short* means = (unsigned short*)alloc((size_t)2 * 32768 * 768 * 2); // 96 MB

    float* out0 = (float*)d_out;
    float* out1 = out0 + 98304;

    // ---- 1: fused prep (zero region + all casts/transposes) ----
    prep_all<<<27415, 256, 0, stream>>>(ent, entB, hidden, hiddenB, wd, wdT,
                                        w1, w1T, wm, wmP, (v4i*)zbase);

    // ---- 2-3: projection prep GEMMs ----
    // pd[e,p] = ent @ wd
    gemm_bt<<<dim3(3, 8), 256, 0, stream>>>(entB, wdT, pd, nullptr, nullptr,
                                            nullptr, nullptr, nullptr,
                                            1000, 300, 768, 768, 768, 320, 0, 0,
                                            0, 0, 0, 0);
    // W2t[e,h] = sum_p pd[e,p]*wm[h,p]
    gemm_bt<<<dim3(6, 8), 256, 0, stream>>>(pd, wmP, W2t, nullptr, nullptr,
                                            nullptr, nullptr, nullptr,
                                            1000, 768, 320, 320, 320, 768, 0, 0,
                                            0, 0, 0, 0);

    // ---- 4-6: bio path (bf16 MFMA + fused epilogue, then exact rescue) ----
    gemm_bt<<<dim3(6, 256), 256, 0, stream>>>(hiddenB, w1T, nullptr, nullptr, nullptr,
                                              b1, w2, part,
                                              32768, 768, 768, 768, 768, 0, 3, 0,
                                              0, 0, 0, 0);
    bio_final2<<<128, 256, 0, stream>>>(part, b2, out0, predLab, flagCnt, flagList);
    h1_bio_gemm<<<dim3(FLAG_CAP / 64, 12), dim3(16, 16), 0, stream>>>(
        hidden, flagList, w1, b1, w2, partF, flagCnt, FLAG_CAP * 3);

    // ---- 7-10: both label sets in one pipeline (y/z = set) ----
    seg_prep2<<<2, 1024, 0, stream>>>(labels, predLab, streamTok, cumArr, meta, rowC,
                                      mapArr, segFirst, partF, b2, flagList, flagCnt,
                                      FLAG_CAP * 3);
    seg_means2<<<dim3(32768, 2), 192, 0, stream>>>(hiddenB, streamTok, segFirst, meta,
                                                   means, (size_t)32768 * 768);
    gemm_bt<<<dim3(8, 256, 2), 256, 0, stream>>>(means, W2t, out1, meta, mapArr,
                                                 nullptr, nullptr, nullptr,
                                                 0, 1000, 768, 768, 768, 1000, 2, 0,
                                                 (size_t)32768 * 768, 64, 32768,
                                                 (size_t)32768 * 1000);
    softmax_rows2<<<dim3(32768, 2), 256, 0, stream>>>(out1, rowC, (size_t)32768 * 1000);
}

// Round 8
// 762.893 us; speedup vs baseline: 1.0249x; 1.0249x over previous
//
#include <hip/hip_runtime.h>
#include <stdint.h>

// ---------- helpers ----------
__device__ inline float bf2f(unsigned short u) { return __uint_as_float(((unsigned int)u) << 16); }
__device__ inline unsigned short f2bf(float f) {
    unsigned int x = __float_as_uint(f);
    unsigned int r = x + 0x7fffu + ((x >> 16) & 1u);   // RNE
    return (unsigned short)(r >> 16);
}

typedef __attribute__((ext_vector_type(8))) short bf16x8;
typedef __attribute__((ext_vector_type(4))) float f32x4;
typedef __attribute__((ext_vector_type(4))) int   v4i;
typedef __attribute__((ext_vector_type(4))) unsigned short u16x4;

#define FLAG_CAP 8192
#define MARGIN 0.02

// async global->LDS, 16B per lane; LDS dest = wave-uniform base + lane*16
__device__ inline void gload16(const void* g, void* l) {
    __builtin_amdgcn_global_load_lds(
        (const __attribute__((address_space(1))) void*)g,
        (__attribute__((address_space(3))) void*)l, 16, 0, 0);
}

// ---------- MFMA GEMM: C[M,N] = A[M,K] * Bt[N,K]^T (A,Bt bf16) ----------
// grid: x = n-tile (fast), y = m-tile, z = optional set index (score path).
// K-loop: BK=32, double-buffered (stage k+1 into buf^1 before computing k; one
// vmcnt-draining __syncthreads per step). R6: 789 -> 766us vs BK=64 single-buf.
// Kept as a single __global__ with RUNTIME dims: R5 showed const-folded K (merged
// launch) regressed ~30% (full-unroll bloat). No XCD swizzle (R2: +2.4%, cf. m160).
// mode 0: store bf16. mode 2: store f32 with rowMap scatter.
// mode 3: fused bio epilogue: atomicAdd fpart[row][c] += sum_n relu(v+fb1[n])*fw2[n][c]
__global__ __launch_bounds__(256) void gemm_bt(
    const unsigned short* __restrict__ A,
    const unsigned short* __restrict__ Bt,
    void* __restrict__ C,
    const int* __restrict__ Mdev,
    const int* __restrict__ rowMap,
    const float* __restrict__ fb1,
    const float* __restrict__ fw2,
    float* __restrict__ fpart,
    int M, int N, int K, int lda, int ldb, int ldc, int mode, int rowOff,
    size_t zA, int zMeta, int zMap, size_t zC)
{
    int zz = blockIdx.z;
    A += (size_t)zz * zA;
    if (Mdev) M = Mdev[zz * zMeta];
    if (rowMap) rowMap += (size_t)zz * zMap;

    int nt = blockIdx.x, mt = blockIdx.y;
    if (rowOff + mt * 128 >= M) return;

    __shared__ __align__(16) unsigned short As[2][128 * 32];
    __shared__ __align__(16) unsigned short Bs[2][128 * 32];

    int tid  = threadIdx.x;
    int lane = tid & 63, wave = tid >> 6;
    int wRow = (wave >> 1) * 64, wCol = (wave & 1) * 64;
    int mBase = mt * 128, nBase = nt * 128;
    int lm = lane & 15, kg = lane >> 4;
    int sr = tid >> 2;            // staging row 0..63 (+64*i)
    int sc = (tid & 3) * 8;       // staging col (8 elems = 16B)

    // Staging layout: element idx = tid*8 + i*2048 in a [128][32] tile ->
    // LDS dest = wave-uniform (wave*512 + i*2048 elems) + lane*16B  (DMA-legal).
    auto STAGE = [&](int k0, int buf) {
#pragma unroll
        for (int i = 0; i < 2; ++i) {
            int r = sr + 64 * i;
            int gm = rowOff + mBase + r; if (gm > M - 1) gm = M - 1;
            gload16(&A[(size_t)(gm - rowOff) * lda + k0 + sc], &As[buf][wave * 512 + i * 2048]);
            int gn = nBase + r; if (gn > N - 1) gn = N - 1;
            gload16(&Bt[(size_t)gn * ldb + k0 + sc], &Bs[buf][wave * 512 + i * 2048]);
        }
    };

    f32x4 acc[4][4] = {};

    STAGE(0, 0);
    __syncthreads();                       // drains vmcnt(0): buf0 ready
    int nsteps = K >> 5;
    for (int s = 0; s < nsteps; ++s) {
        int cur = s & 1;
        if (s + 1 < nsteps) STAGE((s + 1) << 5, cur ^ 1);   // overlap w/ compute
        bf16x8 af[4], bfr[4];
#pragma unroll
        for (int i = 0; i < 4; ++i) {
            af[i]  = *(const bf16x8*)&As[cur][(wRow + i * 16 + lm) * 32 + kg * 8];
            bfr[i] = *(const bf16x8*)&Bs[cur][(wCol + i * 16 + lm) * 32 + kg * 8];
        }
#pragma unroll
        for (int mi = 0; mi < 4; ++mi)
#pragma unroll
            for (int ni = 0; ni < 4; ++ni)
                acc[mi][ni] = __builtin_amdgcn_mfma_f32_16x16x32_bf16(
                    af[mi], bfr[ni], acc[mi][ni], 0, 0, 0);
        __syncthreads();                   // drains vmcnt(0): next buf ready;
    }                                      // also fences reads of cur before reuse

    int rbase = (lane >> 4) * 4;

    if (mode == 3) {
        float b1v[4], w2l[4][3];
#pragma unroll
        for (int ni = 0; ni < 4; ++ni) {
            int n = nBase + wCol + ni * 16 + lm;
            b1v[ni] = fb1[n];
#pragma unroll
            for (int c = 0; c < 3; ++c) w2l[ni][c] = fw2[n * 3 + c];
        }
#pragma unroll
        for (int mi = 0; mi < 4; ++mi) {
            float p2[4][3] = {};
#pragma unroll
            for (int ni = 0; ni < 4; ++ni)
#pragma unroll
                for (int r = 0; r < 4; ++r) {
                    float v = acc[mi][ni][r] + b1v[ni];
                    v = fmaxf(v, 0.f);
                    p2[r][0] += v * w2l[ni][0];
                    p2[r][1] += v * w2l[ni][1];
                    p2[r][2] += v * w2l[ni][2];
                }
#pragma unroll
            for (int r = 0; r < 4; ++r)
#pragma unroll
                for (int c = 0; c < 3; ++c) {
                    float s = p2[r][c];
                    s += __shfl_down(s, 8); s += __shfl_down(s, 4);
                    s += __shfl_down(s, 2); s += __shfl_down(s, 1);
                    p2[r][c] = s;
                }
            if (lm == 0) {
#pragma unroll
                for (int r = 0; r < 4; ++r) {
                    int row = mBase + wRow + mi * 16 + rbase + r;
#pragma unroll
                    for (int c = 0; c < 3; ++c)
                        atomicAdd(&fpart[(size_t)row * 3 + c], p2[r][c]);
                }
            }
        }
        return;
    }

#pragma unroll
    for (int mi = 0; mi < 4; ++mi) {
#pragma unroll
        for (int r = 0; r < 4; ++r) {
            int m = rowOff + mBase + wRow + mi * 16 + rbase + r;
            if (m >= M) continue;
            size_t crow = rowMap ? (size_t)rowMap[m] * ldc : (size_t)(m - rowOff) * ldc;
#pragma unroll
            for (int ni = 0; ni < 4; ++ni) {
                int n = nBase + wCol + ni * 16 + lm;
                if (n >= N) continue;
                float v = acc[mi][ni][r];
                if (mode == 2) ((float*)C)[(size_t)zz * zC + crow + n] = v;
                else           ((unsigned short*)C)[crow + n] = f2bf(v);
            }
        }
    }
}

// ---------- single fused prep kernel ----------
// block ranges: [0,373) zero-fill region | [373,1123) ent cast | [1123,25699) hidden cast
//             | [25699,26515) transposes (wd, w1) | [26515,27415) wm cast_pad
__global__ __launch_bounds__(256) void prep_all(
    const float* __restrict__ ent, unsigned short* __restrict__ entB,
    const float* __restrict__ hidden, unsigned short* __restrict__ hiddenB,
    const float* __restrict__ wd, unsigned short* __restrict__ wdT,
    const float* __restrict__ w1, unsigned short* __restrict__ w1T,
    const float* __restrict__ wm, unsigned short* __restrict__ wmP,
    v4i* __restrict__ zreg)
{
    __shared__ float tile[32][33];
    int b = blockIdx.x, t = threadIdx.x;
    if (b < 373) {
        int i = b * 256 + t;
        if (i < 95312) { v4i z = {0, 0, 0, 0}; zreg[i] = z; }
        return;
    }
    b -= 373;
    if (b < 750) {                                   // ent: 192000 float4
        int i = b * 256 + t;
        float4 v = ((const float4*)ent)[i];
        u16x4 o = { f2bf(v.x), f2bf(v.y), f2bf(v.z), f2bf(v.w) };
        ((u16x4*)entB)[i] = o;
        return;
    }
    b -= 750;
    if (b < 24576) {                                 // hidden: 6291456 float4
        int i = b * 256 + t;
        float4 v = ((const float4*)hidden)[i];
        u16x4 o = { f2bf(v.x), f2bf(v.y), f2bf(v.z), f2bf(v.w) };
        ((u16x4*)hiddenB)[i] = o;
        return;
    }
    b -= 24576;
    if (b < 240 + 576) {                             // transpose_cast wd / w1
        const float* in; unsigned short* out; int R, C, bx, by;
        if (b < 240) { in = wd; out = wdT; R = 768; C = 300; bx = b % 10; by = b / 10; }
        else { int bb = b - 240; in = w1; out = w1T; R = 768; C = 768; bx = bb % 24; by = bb / 24; }
        int tx = t & 31, ty = t >> 5;
        int c0 = bx * 32, r0 = by * 32;
#pragma unroll
        for (int i = 0; i < 4; ++i) {
            int r = r0 + ty + i * 8, c = c0 + tx;
            if (r < R && c < C) tile[ty + i * 8][tx] = in[(size_t)r * C + c];
        }
        __syncthreads();
#pragma unroll
        for (int i = 0; i < 4; ++i) {
            int orow = c0 + ty + i * 8, ocol = r0 + tx;
            if (orow < C && ocol < R) out[(size_t)orow * R + ocol] = f2bf(tile[tx][ty + i * 8]);
        }
        return;
    }
    b -= 816;
    {                                                // wm cast_pad 768x300 -> ld 320
        int idx = b * 256 + t;
        if (idx < 768 * 300) wmP[(size_t)(idx / 300) * 320 + (idx % 300)] = f2bf(wm[idx]);
    }
}

// ---------- finalize approx logits, flag marginal tokens ----------
__global__ void bio_final2(const float* __restrict__ part, const float* __restrict__ b2,
                           float* __restrict__ out0, int* __restrict__ predLab,
                           int* __restrict__ flagCnt, int* __restrict__ flagList)
{
    int t = blockIdx.x * 256 + threadIdx.x;
    double a[3];
#pragma unroll
    for (int c = 0; c < 3; ++c) a[c] = (double)part[(size_t)t * 3 + c] + (double)b2[c];
    double mx = a[0]; if (a[1] > mx) mx = a[1]; if (a[2] > mx) mx = a[2];
    double ls = mx + log(exp(a[0] - mx) + exp(a[1] - mx) + exp(a[2] - mx));
    out0[t * 3 + 0] = (float)(a[0] - ls);
    out0[t * 3 + 1] = (float)(a[1] - ls);
    out0[t * 3 + 2] = (float)(a[2] - ls);
    int pbest = 0; double bv = a[0];
    if (a[1] > bv) { bv = a[1]; pbest = 1; }
    if (a[2] > bv) { bv = a[2]; pbest = 2; }
    predLab[t] = pbest;
    double second = -1e300;
#pragma unroll
    for (int c = 0; c < 3; ++c) if (c != pbest && a[c] > second) second = a[c];
    if (bv - second < MARGIN) {
        int i = atomicAdd(flagCnt, 1);
        if (i < FLAG_CAP) flagList[i] = t;
    }
}

// ---------- exact f32 h1+partial-logit GEMM on flagged rows (reads hidden via flagList) ----------
__global__ __launch_bounds__(256) void h1_bio_gemm(
    const float* __restrict__ hidden, const int* __restrict__ flagList,
    const float* __restrict__ W,
    const float* __restrict__ b1, const float* __restrict__ w2,
    float* __restrict__ part, const int* __restrict__ Mdev, int partStride)
{
    int M = *Mdev; if (M > FLAG_CAP) M = FLAG_CAP;
    if (M <= 0) return;
    int m0 = blockIdx.x * 64, n0 = blockIdx.y * 64;
    if (m0 >= M) return;
    __shared__ float AsT[16][64];
    __shared__ float Ws[16][64];
    int tx = threadIdx.x, ty = threadIdx.y;
    int tid = ty * 16 + tx;
    float acc[4][4] = {};

    for (int k0 = 0; k0 < 768; k0 += 16) {
        __syncthreads();
        {
            int row = tid >> 2, seg = (tid & 3) * 4;
            int gm = m0 + row; if (gm > M - 1) gm = M - 1;
            float4 v = *(const float4*)&hidden[(size_t)flagList[gm] * 768 + k0 + seg];
            AsT[seg + 0][row] = v.x; AsT[seg + 1][row] = v.y;
            AsT[seg + 2][row] = v.z; AsT[seg + 3][row] = v.w;
        }
        {
            int row = tid >> 4, seg = (tid & 15) * 4;
            *(float4*)&Ws[row][seg] = *(const float4*)&W[(size_t)(k0 + row) * 768 + n0 + seg];
        }
        __syncthreads();
#pragma unroll
        for (int kk = 0; kk < 16; ++kk) {
            float4 av = *(const float4*)&AsT[kk][ty * 4];
            float4 bv = *(const float4*)&Ws[kk][tx * 4];
            float a[4] = {av.x, av.y, av.z, av.w};
            float b[4] = {bv.x, bv.y, bv.z, bv.w};
#pragma unroll
            for (int i = 0; i < 4; ++i)
#pragma unroll
                for (int j = 0; j < 4; ++j)
                    acc[i][j] += a[i] * b[j];
        }
    }

    float b1v[4], w2l[4][3];
#pragma unroll
    for (int j = 0; j < 4; ++j) {
        int n = n0 + tx * 4 + j;
        b1v[j] = b1[n];
#pragma unroll
        for (int c = 0; c < 3; ++c) w2l[j][c] = w2[n * 3 + c];
    }
    float p[4][3] = {};
#pragma unroll
    for (int i = 0; i < 4; ++i)
#pragma unroll
        for (int j = 0; j < 4; ++j) {
            float v = acc[i][j] + b1v[j];
            v = fmaxf(v, 0.f);
#pragma unroll
            for (int c = 0; c < 3; ++c) p[i][c] += v * w2l[j][c];
        }
#pragma unroll
    for (int i = 0; i < 4; ++i)
#pragma unroll
        for (int c = 0; c < 3; ++c) {
            float s = p[i][c];
            s += __shfl_down(s, 8); s += __shfl_down(s, 4);
            s += __shfl_down(s, 2); s += __shfl_down(s, 1);
            p[i][c] = s;
        }
    if (tx == 0) {
#pragma unroll
        for (int i = 0; i < 4; ++i) {
            int t = m0 + ty * 4 + i;
            if (t >= M) continue;
#pragma unroll
            for (int c = 0; c < 3; ++c)
                part[(size_t)blockIdx.y * partStride + (size_t)t * 3 + c] = p[i][c];
        }
    }
}

// ---------- exact argmax for flagged tokens ----------
__global__ void bio_final_fix(const float* __restrict__ partF, const float* __restrict__ b2,
                              const int* __restrict__ flagList, const int* __restrict__ flagCnt,
                              int* __restrict__ predLab, int partStride)
{
    int i = blockIdx.x * 256 + threadIdx.x;
    int cnt = *flagCnt; if (cnt > FLAG_CAP) cnt = FLAG_CAP;
    if (i >= cnt) return;
    double a[3] = {(double)b2[0], (double)b2[1], (double)b2[2]};
#pragma unroll
    for (int blk = 0; blk < 12; ++blk)
#pragma unroll
        for (int c = 0; c < 3; ++c)
            a[c] += (double)partF[(size_t)blk * partStride + (size_t)i * 3 + c];
    int pbest = 0; double bv = a[0];
    if (a[1] > bv) { bv = a[1]; pbest = 1; }
    if (a[2] > bv) { bv = a[2]; pbest = 2; }
    predLab[flagList[i]] = pbest;
}

// ---------- merged segmentation prep, both sets (block 0 = true, block 1 = predicted) ----------
// meta[set*64 + {0,1,2}] = numB, K, idx0
__global__ __launch_bounds__(1024) void seg_prep2(
    const int* __restrict__ labels, const int* __restrict__ predLab,
    int* __restrict__ streamTok, int* __restrict__ cumArr,
    int* __restrict__ meta, int* __restrict__ rowC, int* __restrict__ mapArr)
{
    int setz = blockIdx.x;
    const int* lab = setz ? predLab : labels;
    int* sTok = streamTok + setz * 32768;
    int* sCum = cumArr + setz * 32768;
    int* mt   = meta + setz * 64;
    int* rC   = rowC + setz * 64;
    int* mp   = mapArr + setz * 32768;

    __shared__ int sM[1024], sB[1024];
    __shared__ int sRowC[64], sRowStart[64];
    __shared__ int sIdx0;
    int t = threadIdx.x;
    if (t == 0) sIdx0 = 0x7fffffff;
    int base = t * 32;
    int vals[32];
#pragma unroll
    for (int j = 0; j < 8; ++j) {
        v4i v = ((const v4i*)lab)[t * 8 + j];
        vals[4 * j + 0] = v[0]; vals[4 * j + 1] = v[1];
        vals[4 * j + 2] = v[2]; vals[4 * j + 3] = v[3];
    }
    int mc = 0, bc = 0;
#pragma unroll
    for (int i = 0; i < 32; ++i) { mc += (vals[i] != 0); bc += (vals[i] == 1); }
    sM[t] = mc; sB[t] = bc; __syncthreads();
    for (int off = 1; off < 1024; off <<= 1) {
        int vm = 0, vb = 0;
        if (t >= off) { vm = sM[t - off]; vb = sB[t - off]; }
        __syncthreads();
        sM[t] += vm; sB[t] += vb;
        __syncthreads();
    }
    int mBase = sM[t] - mc, bBase = sB[t] - bc;
    int mRun = 0, bRun = 0;
#pragma unroll
    for (int i = 0; i < 32; ++i) {
        int v = vals[i];
        if (v != 0) {
            int q = mBase + mRun;
            sTok[q] = base + i;
            int isB = (v == 1);
            sCum[q] = bBase + bRun + isB;
            if (isB && (bBase + bRun) == 0) sIdx0 = q;   // unique thread
            mRun += 1; bRun += isB;
        }
    }
    if ((t & 15) == 0) sRowStart[t >> 4] = bBase;
    __syncthreads();
    if ((t & 15) == 0) {
        int b = t >> 4;
        sRowC[b] = sB[t + 15] - sRowStart[b];
        rC[b] = sRowC[b];
    }
    if (t == 1023) { mt[0] = sB[1023]; mt[1] = sM[1023]; }
    if (t == 0) mt[2] = (sIdx0 == 0x7fffffff) ? 0 : sIdx0;
    __syncthreads();
    for (int idx = t; idx < 32768; idx += 1024) {
        int b = idx >> 9, j = idx & 511;
        if (j < sRowC[b]) mp[sRowStart[b] + j] = idx;
    }
}

// ---------- atomic-free segment boundaries: seg(q) is nondecreasing in q ----------
__global__ void seg_bound(const int* __restrict__ cumArr, int* __restrict__ segFirst,
                          const int* __restrict__ meta)
{
    int setz = blockIdx.y;
    const int* cum = cumArr + setz * 32768;
    int* sf = segFirst + setz * 32768;
    const int* mt = meta + setz * 64;
    int q = blockIdx.x * 256 + threadIdx.x;
    int K = mt[1];
    if (q >= K) return;
    int numB = mt[0], idx0 = mt[2];
    int qq = q + idx0;
    int c  = (qq < K) ? cum[qq] : numB;
    int sg = c - 1;
    if (sg < 0) return;
    int sp = -1;
    if (q > 0) {
        int qq2 = qq - 1;
        int c2  = (qq2 < K) ? cum[qq2] : numB;
        sp = c2 - 1;
    }
    if (sg != sp) sf[sg] = q;
}

// ---------- means for all segments, both sets (192 thr, u16x4; grid-stride over s) ----------
// Grid-stride removes ~21k early-exit ballast blocks per set (numB << 32768).
// Per-segment work and per-column i-ascending sum order unchanged -> bit-identical.
__global__ __launch_bounds__(192) void seg_means2(
    const unsigned short* __restrict__ hiddenB, const int* __restrict__ streamTok,
    const int* __restrict__ segFirst, const int* __restrict__ meta,
    unsigned short* __restrict__ means, size_t zMeans)
{
    int setz = blockIdx.y;
    const int* mt = meta + setz * 64;
    int numB = mt[0];
    int K = mt[1];
    const int* st = streamTok + setz * 32768;
    const int* sf = segFirst + setz * 32768;
    int t = threadIdx.x;
    for (int s = blockIdx.x; s < numB; s += gridDim.x) {
        int q0 = sf[s];
        int q1 = (s + 1 < numB) ? sf[s + 1] : K;
        int cnt = q1 - q0;                               // >= 1 by construction
        float a0 = 0.f, a1 = 0.f, a2 = 0.f, a3 = 0.f;
        for (int i = 0; i < cnt; ++i) {
            const unsigned short* hr = hiddenB + (size_t)st[q0 + i] * 768;
            u16x4 v = *(const u16x4*)&hr[t * 4];
            a0 += bf2f(v[0]); a1 += bf2f(v[1]); a2 += bf2f(v[2]); a3 += bf2f(v[3]);
        }
        float fc = (float)cnt;
        u16x4 o = { f2bf(a0 / fc), f2bf(a1 / fc), f2bf(a2 / fc), f2bf(a3 / fc) };
        *(u16x4*)&means[(size_t)setz * zMeans + (size_t)s * 768 + t * 4] = o;
    }
}

// ---------- in-place row log_softmax over 1000 cols + constant fill, both sets ----------
__global__ __launch_bounds__(256) void softmax_rows2(float* __restrict__ outBase,
                                                     const int* __restrict__ rowCBase,
                                                     size_t zC)
{
    float* out = outBase + (size_t)blockIdx.y * zC;
    const int* rowC = rowCBase + blockIdx.y * 64;
    int v = blockIdx.x;
    int b = v >> 9, j = v & 511;
    int t = threadIdx.x;
    float* row = out + (size_t)v * 1000;
    if (j >= rowC[b]) {
        for (int e = t; e < 1000; e += 256) row[e] = -6.907755278982137f;
        return;
    }
    __shared__ float red[256];
    float x0 = row[t];
    float x1 = row[t + 256];
    float x2 = row[t + 512];
    bool has3 = (t + 768) < 1000;
    float x3 = has3 ? row[t + 768] : -1e30f;
    float mx = fmaxf(fmaxf(x0, x1), fmaxf(x2, x3));
    red[t] = mx; __syncthreads();
    for (int st = 128; st > 0; st >>= 1) { if (t < st) red[t] = fmaxf(red[t], red[t + st]); __syncthreads(); }
    float M = red[0]; __syncthreads();
    float sm = expf(x0 - M) + expf(x1 - M) + expf(x2 - M) + (has3 ? expf(x3 - M) : 0.f);
    red[t] = sm; __syncthreads();
    for (int st = 128; st > 0; st >>= 1) { if (t < st) red[t] += red[t + st]; __syncthreads(); }
    float ls = M + logf(red[0]);
    row[t]       = x0 - ls;
    row[t + 256] = x1 - ls;
    row[t + 512] = x2 - ls;
    if (has3) row[t + 768] = x3 - ls;
}

// ---------- launch ----------
extern "C" void kernel_launch(void* const* d_in, const int* in_sizes, int n_in,
                              void* d_out, int out_size, void* d_ws, size_t ws_size,
                              hipStream_t stream)
{
    (void)in_sizes; (void)n_in; (void)out_size; (void)ws_size;
    const int*   labels = (const int*)d_in[0];
    const float* hidden = (const float*)d_in[1];
    const float* ent    = (const float*)d_in[2];
    const float* w1     = (const float*)d_in[3];
    const float* b1     = (const float*)d_in[4];
    const float* w2     = (const float*)d_in[5];
    const float* b2     = (const float*)d_in[6];
    const float* wm     = (const float*)d_in[7];
    const float* wd     = (const float*)d_in[8];

    char* ws = (char*)d_ws;
    size_t off = 0;
    auto alloc = [&](size_t bytes) {
        void* p = ws + off;
        off = (off + bytes + 255) & ~(size_t)255;
        return p;
    };
    int* meta      = (int*)alloc(512);                    // 2 sets x 64 ints
    int* rowC      = (int*)alloc(512);
    int* predLab   = (int*)alloc(32768 * 4);
    int* streamTok = (int*)alloc(2 * 32768 * 4);
    int* cumArr    = (int*)alloc(2 * 32768 * 4);
    int* segFirst  = (int*)alloc(2 * 32768 * 4);
    int* mapArr    = (int*)alloc(2 * 32768 * 4);
    int* flagList  = (int*)alloc(FLAG_CAP * 4);
    unsigned short* entB = (unsigned short*)alloc((size_t)1000 * 768 * 2);
    unsigned short* wdT  = (unsigned short*)alloc((size_t)300 * 768 * 2);
    unsigned short* W2t  = (unsigned short*)alloc((size_t)1000 * 768 * 2);
    unsigned short* w1T  = (unsigned short*)alloc((size_t)768 * 768 * 2);
    unsigned short* hiddenB = (unsigned short*)alloc((size_t)32768 * 768 * 2);   // 48 MB
    float* partF = (float*)alloc((size_t)12 * FLAG_CAP * 3 * 4);
    // contiguous zero region cleared by prep_all: [pd | wmP | part | flagCnt]
    char* zbase = (char*)alloc(1524992);
    unsigned short* pd  = (unsigned short*)zbase;                 // 1000x320 bf16 = 640000 B
    unsigned short* wmP = (unsigned short*)(zbase + 640000);      // 768x320 bf16  = 491520 B
    float* part         = (float*)(zbase + 1131520);              // 32768x3 f32   = 393216 B
    int* flagCnt        = (int*)(zbase + 1524736);                // 256 B
    unsigned short* means = (unsigned short*)alloc((size_t)2 * 32768 * 768 * 2); // 96 MB

    float* out0 = (float*)d_out;
    float* out1 = out0 + 98304;

    // ---- 1: fused prep (zero region + all casts/transposes) ----
    prep_all<<<27415, 256, 0, stream>>>(ent, entB, hidden, hiddenB, wd, wdT,
                                        w1, w1T, wm, wmP, (v4i*)zbase);

    // ---- 2-3: projection prep GEMMs ----
    // pd[e,p] = ent @ wd
    gemm_bt<<<dim3(3, 8), 256, 0, stream>>>(entB, wdT, pd, nullptr, nullptr,
                                            nullptr, nullptr, nullptr,
                                            1000, 300, 768, 768, 768, 320, 0, 0,
                                            0, 0, 0, 0);
    // W2t[e,h] = sum_p pd[e,p]*wm[h,p]
    gemm_bt<<<dim3(6, 8), 256, 0, stream>>>(pd, wmP, W2t, nullptr, nullptr,
                                            nullptr, nullptr, nullptr,
                                            1000, 768, 320, 320, 320, 768, 0, 0,
                                            0, 0, 0, 0);

    // ---- 4-7: bio path (bf16 MFMA + fused epilogue, then exact rescue) ----
    gemm_bt<<<dim3(6, 256), 256, 0, stream>>>(hiddenB, w1T, nullptr, nullptr, nullptr,
                                              b1, w2, part,
                                              32768, 768, 768, 768, 768, 0, 3, 0,
                                              0, 0, 0, 0);
    bio_final2<<<128, 256, 0, stream>>>(part, b2, out0, predLab, flagCnt, flagList);
    h1_bio_gemm<<<dim3(FLAG_CAP / 64, 12), dim3(16, 16), 0, stream>>>(
        hidden, flagList, w1, b1, w2, partF, flagCnt, FLAG_CAP * 3);
    bio_final_fix<<<FLAG_CAP / 256, 256, 0, stream>>>(partF, b2, flagList, flagCnt,
                                                      predLab, FLAG_CAP * 3);

    // ---- 8-12: both label sets in one pipeline (y/z = set) ----
    seg_prep2<<<2, 1024, 0, stream>>>(labels, predLab, streamTok, cumArr, meta, rowC, mapArr);
    seg_bound<<<dim3(128, 2), 256, 0, stream>>>(cumArr, segFirst, meta);
    seg_means2<<<dim3(4096, 2), 192, 0, stream>>>(hiddenB, streamTok, segFirst, meta,
                                                  means, (size_t)32768 * 768);
    gemm_bt<<<dim3(8, 256, 2), 256, 0, stream>>>(means, W2t, out1, meta, mapArr,
                                                 nullptr, nullptr, nullptr,
                                                 0, 1000, 768, 768, 768, 1000, 2, 0,
                                                 (size_t)32768 * 768, 64, 32768,
                                                 (size_t)32768 * 1000);
    softmax_rows2<<<dim3(32768, 2), 256, 0, stream>>>(out1, rowC, (size_t)32768 * 1000);
}